// Round 1
// baseline (5865.992 us; speedup 1.0000x reference)
//
#include <hip/hip_runtime.h>
#include <math.h>

#define KGRID 1024
#define NIMG  512
#define JW    6
#define BETAF 14.04f   // 2.34 * J
#define MAXB  8

// ---------- Kaiser-Bessel I0 (Abramowitz & Stegun 9.8.1 / 9.8.2, ~2e-7 rel) ----------
__device__ __forceinline__ float i0f_dev(float x) {
    float ax = fabsf(x);
    if (ax < 3.75f) {
        float z = ax * (1.0f / 3.75f);
        z = z * z;
        return 1.0f + z * (3.5156229f + z * (3.0899424f + z * (1.2067492f +
               z * (0.2659732f + z * (0.0360768f + z * 0.0045813f)))));
    } else {
        float z = 3.75f / ax;
        float p = 0.39894228f + z * (0.01328592f + z * (0.00225319f + z * (-0.00157565f +
                  z * (0.00916281f + z * (-0.02057706f + z * (0.02635537f +
                  z * (-0.01647633f + z * 0.00392377f)))))));
        return expf(ax) * rsqrtf(ax) * p;
    }
}

__device__ __forceinline__ void atomAddF(float* p, float v) {
    unsafeAtomicAdd(p, v);   // native global_atomic_add_f32 on gfx950
}

// ---------- Gridding: scatter-add KB-weighted visibilities onto (bc, K, K) complex grid ----------
__global__ __launch_bounds__(256) void grid_kernel(
    const float* __restrict__ uv, const float* __restrict__ wts,
    const float* __restrict__ yr, const float* __restrict__ yi,
    float2* __restrict__ grid, int M, int b0, int bc)
{
    int m = blockIdx.x * blockDim.x + threadIdx.x;
    if (m >= M) return;

    float inv_i0b = 1.0f / i0f_dev(BETAF);
    float scale = wts[m] * inv_i0b * inv_i0b;   // fold both 1/I0(beta) factors + weight

    float u = uv[2 * m];
    float v = uv[2 * m + 1];

    int   ix[JW], iy[JW];
    float wx[JW], wy[JW];

    {
        float k = u / 6.283185307179586f * (float)KGRID;
        float km = floorf(k - 3.0f);
        #pragma unroll
        for (int j = 0; j < JW; j++) {
            float pt = km + (float)(j + 1);
            float d = k - pt;
            float r = 2.0f * d * (1.0f / (float)JW);
            float a = fmaxf(1.0f - r * r, 0.0f);
            wx[j] = i0f_dev(BETAF * sqrtf(a));
            ix[j] = (((int)pt) + KGRID) & (KGRID - 1);
        }
    }
    {
        float k = v / 6.283185307179586f * (float)KGRID;
        float km = floorf(k - 3.0f);
        #pragma unroll
        for (int j = 0; j < JW; j++) {
            float pt = km + (float)(j + 1);
            float d = k - pt;
            float r = 2.0f * d * (1.0f / (float)JW);
            float a = fmaxf(1.0f - r * r, 0.0f);
            wy[j] = i0f_dev(BETAF * sqrtf(a));
            iy[j] = (((int)pt) + KGRID) & (KGRID - 1);
        }
    }

    float yrv[MAXB], yiv[MAXB];
    for (int b = 0; b < bc; b++) {
        yrv[b] = yr[(size_t)(b0 + b) * M + m] * scale;
        yiv[b] = yi[(size_t)(b0 + b) * M + m] * scale;
    }

    const size_t plane = (size_t)KGRID * KGRID;
    #pragma unroll
    for (int j1 = 0; j1 < JW; j1++) {
        int rowb = ix[j1] << 10;
        float wxx = wx[j1];
        #pragma unroll
        for (int j2 = 0; j2 < JW; j2++) {
            float w = wxx * wy[j2];
            int cell = rowb + iy[j2];
            for (int b = 0; b < bc; b++) {
                float* p = (float*)&grid[(size_t)b * plane + cell];
                atomAddF(p,     yrv[b] * w);
                atomAddF(p + 1, yiv[b] * w);
            }
        }
    }
}

// ---------- Stockham radix-2 1024-pt inverse (e^{+i}) FFT in LDS ----------
// Verified mapping per stage (s = 1<<stage): t in [0,512),
//   sp = t & ~(s-1);  in0 = t, in1 = t+512;  out0 = t+sp (sum), out1 = out0+s ((a-b)*W[sp])
// 10 stages, ping-pong X<->Y; result lands back in X.
__device__ __forceinline__ void fft1024_inv(float2* X, float2* Y, const float2* W, int tid)
{
    float2* src = X;
    float2* dst = Y;
    #pragma unroll
    for (int stage = 0; stage < 10; stage++) {
        const int s = 1 << stage;
        __syncthreads();
        #pragma unroll
        for (int h = 0; h < 2; h++) {
            int t  = tid + (h << 8);
            int sp = t & ~(s - 1);
            float2 c0 = src[t];
            float2 c1 = src[t + 512];
            float2 sum = make_float2(c0.x + c1.x, c0.y + c1.y);
            float2 dif = make_float2(c0.x - c1.x, c0.y - c1.y);
            float2 w = W[sp];
            dst[t + sp]     = sum;
            dst[t + sp + s] = make_float2(w.x * dif.x - w.y * dif.y,
                                          w.x * dif.y + w.y * dif.x);
        }
        float2* tmp = src; src = dst; dst = tmp;
    }
    __syncthreads();
}

// ---------- Pass 1: rows (k2 -> x2), keep 512 shifted/cropped columns, store transposed ----------
__global__ __launch_bounds__(256) void fft_pass1(const float2* __restrict__ grid,
                                                 float2* __restrict__ T)
{
    __shared__ float2 A[1024];
    __shared__ float2 Bb[1024];
    __shared__ float2 W[512];

    int blk = blockIdx.x;
    int cb  = blk >> 10;          // chunk-local batch
    int k1  = blk & 1023;
    int tid = threadIdx.x;

    const float2* row = grid + ((size_t)cb << 20) + ((size_t)k1 << 10);
    #pragma unroll
    for (int h = 0; h < 4; h++) { int i = tid + (h << 8); A[i] = row[i]; }
    #pragma unroll
    for (int h = 0; h < 2; h++) {
        int j = tid + (h << 8);
        float sn, cn;
        __sincosf(6.283185307179586f * (float)j * (1.0f / 1024.0f), &sn, &cn);
        W[j] = make_float2(cn, sn);   // +i for inverse
    }

    fft1024_inv(A, Bb, W, tid);

    // out column xo2 corresponds to x2 = (xo2 + 768) & 1023 (fftshift + crop fold)
    float2* Tb = T + (((size_t)cb * 512) << 10) + k1;
    #pragma unroll
    for (int h = 0; h < 2; h++) {
        int xo2 = tid + (h << 8);
        int x2  = (xo2 + 768) & 1023;
        Tb[(size_t)xo2 << 10] = A[x2];
    }
}

// ---------- de-apodization (matches _deapod) ----------
__device__ __forceinline__ float apodf(int n) {
    float x  = ((float)n - 256.0f) * (1.0f / 1024.0f);
    float px = 3.14159265358979f * 6.0f * x;
    float t  = BETAF * BETAF - px * px;
    float st = sqrtf(fabsf(t));
    float num = (t > 0.0f) ? sinhf(st) : __sinf(st);
    return num / fmaxf(st, 1e-6f);
}

// ---------- Pass 2: columns (k1 -> x1), fuse shift/crop/real/de-apod into store ----------
__global__ __launch_bounds__(256) void fft_pass2(const float2* __restrict__ T,
                                                 float* __restrict__ out, int b0)
{
    __shared__ float2 A[1024];
    __shared__ float2 Bb[1024];
    __shared__ float2 W[512];

    int blk = blockIdx.x;
    int cb  = blk >> 9;
    int xo2 = blk & 511;
    int tid = threadIdx.x;

    const float2* row = T + (((size_t)cb * 512 + xo2) << 10);
    #pragma unroll
    for (int h = 0; h < 4; h++) { int i = tid + (h << 8); A[i] = row[i]; }
    #pragma unroll
    for (int h = 0; h < 2; h++) {
        int j = tid + (h << 8);
        float sn, cn;
        __sincosf(6.283185307179586f * (float)j * (1.0f / 1024.0f), &sn, &cn);
        W[j] = make_float2(cn, sn);
    }

    fft1024_inv(A, Bb, W, tid);

    float a2 = apodf(xo2);
    int b = b0 + cb;
    #pragma unroll
    for (int h = 0; h < 2; h++) {
        int xo1 = tid + (h << 8);
        int x1  = (xo1 + 768) & 1023;
        float a1 = apodf(xo1);
        out[((size_t)b * 512 + xo1) * 512 + xo2] = A[x1].x / (a1 * a2);
    }
}

// ---------- host launch ----------
extern "C" void kernel_launch(void* const* d_in, const int* in_sizes, int n_in,
                              void* d_out, int out_size, void* d_ws, size_t ws_size,
                              hipStream_t stream)
{
    const float* yr  = (const float*)d_in[0];
    const float* yi  = (const float*)d_in[1];
    const float* uv  = (const float*)d_in[2];
    const float* wts = (const float*)d_in[3];

    int M = in_sizes[3];
    int B = in_sizes[0] / M;

    const size_t gridBytes = (size_t)KGRID * KGRID * sizeof(float2);  // 8 MB / batch
    const size_t tBytes    = (size_t)NIMG * KGRID * sizeof(float2);   // 4 MB / batch

    int c = (int)(ws_size / (gridBytes + tBytes));
    if (c > B) c = B;
    if (c > MAXB) c = MAXB;
    if (c < 1) c = 1;

    float2* grid = (float2*)d_ws;
    float2* T    = (float2*)((char*)d_ws + (size_t)c * gridBytes);

    for (int b0 = 0; b0 < B; b0 += c) {
        int bc = B - b0; if (bc > c) bc = c;
        hipMemsetAsync(grid, 0, (size_t)bc * gridBytes, stream);
        grid_kernel<<<dim3((M + 255) / 256), dim3(256), 0, stream>>>(
            uv, wts, yr, yi, grid, M, b0, bc);
        fft_pass1<<<dim3(bc * 1024), dim3(256), 0, stream>>>(grid, T);
        fft_pass2<<<dim3(bc * 512), dim3(256), 0, stream>>>(T, (float*)d_out, b0);
    }
}

// Round 2
// 892.048 us; speedup vs baseline: 6.5759x; 6.5759x over previous
//
#include <hip/hip_runtime.h>
#include <math.h>

#define KGRID 1024
#define NIMG  512
#define JW    6
#define BETAF 14.04f   // 2.34 * J
#define NB    8        // batch count (fixed by problem)

// ---------- Kaiser-Bessel I0 (Abramowitz & Stegun 9.8.1 / 9.8.2, ~2e-7 rel) ----------
__device__ __forceinline__ float i0f_dev(float x) {
    float ax = fabsf(x);
    if (ax < 3.75f) {
        float z = ax * (1.0f / 3.75f);
        z = z * z;
        return 1.0f + z * (3.5156229f + z * (3.0899424f + z * (1.2067492f +
               z * (0.2659732f + z * (0.0360768f + z * 0.0045813f)))));
    } else {
        float z = 3.75f / ax;
        float p = 0.39894228f + z * (0.01328592f + z * (0.00225319f + z * (-0.00157565f +
                  z * (0.00916281f + z * (-0.02057706f + z * (0.02635537f +
                  z * (-0.01647633f + z * 0.00392377f)))))));
        return expf(ax) * rsqrtf(ax) * p;
    }
}

// ---------- Gridding onto batch-interleaved grid: gI[cell][b] (float2) ----------
// One wave per measurement iteration. Lane l: j2 = l>>3 (y-tap), b = l&7.
// For each j1 (x-tap), the 48 active lanes write 96 CONSECUTIVE floats
// (6 cells x 8 batches x {re,im}) -> 6 full 64B lines per tap-row instead of
// 48 scattered lines. This is the whole optimization.
__global__ __launch_bounds__(256) void grid_kernel(
    const float* __restrict__ uv, const float* __restrict__ wts,
    const float* __restrict__ yr, const float* __restrict__ yi,
    float* __restrict__ gI, int M)
{
    int gtid  = blockIdx.x * blockDim.x + threadIdx.x;
    int wave  = gtid >> 6;
    int lane  = threadIdx.x & 63;
    int nWaves = (gridDim.x * blockDim.x) >> 6;

    int j2 = lane >> 3;      // 0..7, active if < 6
    int b  = lane & 7;
    bool active = (j2 < JW);

    float inv_i0b = 1.0f / i0f_dev(BETAF);
    float s2 = inv_i0b * inv_i0b;
    const float c2g = (float)KGRID / 6.283185307179586f;

    for (int m = wave; m < M; m += nWaves) {
        float u = uv[2 * m];
        float v = uv[2 * m + 1];
        float scale = wts[m] * s2;

        // per-lane y values for this lane's batch
        float yrl = yr[(size_t)b * M + m] * scale;
        float yil = yi[(size_t)b * M + m] * scale;

        // y-axis tap for this lane's j2
        float ky  = v * c2g;
        float kmy = floorf(ky - 3.0f);
        float pty = kmy + (float)(j2 + 1);
        float dy  = ky - pty;
        float ry  = dy * (1.0f / 3.0f);
        float ay  = fmaxf(1.0f - ry * ry, 0.0f);
        float wyl = i0f_dev(BETAF * sqrtf(ay));
        int   iy  = (((int)pty) + KGRID) & (KGRID - 1);

        // x-axis: loop over 6 taps (uniform across lanes)
        float kx  = u * c2g;
        float kmx = floorf(kx - 3.0f);
        #pragma unroll
        for (int j1 = 0; j1 < JW; j1++) {
            float ptx = kmx + (float)(j1 + 1);
            float dx  = kx - ptx;
            float rx  = dx * (1.0f / 3.0f);
            float ax  = fmaxf(1.0f - rx * rx, 0.0f);
            float wx  = i0f_dev(BETAF * sqrtf(ax));
            int   ixr = (((int)ptx) + KGRID) & (KGRID - 1);
            if (active) {
                float w = wx * wyl;
                size_t fidx = ((((size_t)ixr << 10) + (size_t)iy) << 4) + ((size_t)b << 1);
                unsafeAtomicAdd(gI + fidx,     yrl * w);
                unsafeAtomicAdd(gI + fidx + 1, yil * w);
            }
        }
    }
}

// ---------- Stockham radix-2 1024-pt inverse (e^{+i}) FFT in LDS ----------
__device__ __forceinline__ void fft1024_inv(float2* X, float2* Y, const float2* W, int tid)
{
    float2* src = X;
    float2* dst = Y;
    #pragma unroll
    for (int stage = 0; stage < 10; stage++) {
        const int s = 1 << stage;
        __syncthreads();
        #pragma unroll
        for (int h = 0; h < 2; h++) {
            int t  = tid + (h << 8);
            int sp = t & ~(s - 1);
            float2 c0 = src[t];
            float2 c1 = src[t + 512];
            float2 sum = make_float2(c0.x + c1.x, c0.y + c1.y);
            float2 dif = make_float2(c0.x - c1.x, c0.y - c1.y);
            float2 w = W[sp];
            dst[t + sp]     = sum;
            dst[t + sp + s] = make_float2(w.x * dif.x - w.y * dif.y,
                                          w.x * dif.y + w.y * dif.x);
        }
        float2* tmp = src; src = dst; dst = tmp;
    }
    __syncthreads();
}

// ---------- Pass 1: rows (k2 -> x2) from interleaved grid; keep 512 shifted
// columns; store transposed planar-per-batch into T ----------
// Block swizzle: blk = g*64 + b*8 + r, k1 = g*8+r, b = (blk>>3)&7.
// => blk % 8 depends only on k1 (same XCD for all 8 b of a row, assuming
// round-robin XCD dispatch) and the 8 b-blocks of a row are 8 dispatch
// indices apart -> row's 64KB L2-hits across its 8 readers.
__global__ __launch_bounds__(256) void fft_pass1(const float2* __restrict__ gI,
                                                 float2* __restrict__ T)
{
    __shared__ float2 A[1024];
    __shared__ float2 Bb[1024];
    __shared__ float2 W[512];

    int blk = blockIdx.x;
    int k1  = ((blk >> 6) << 3) | (blk & 7);
    int b   = (blk >> 3) & 7;
    int tid = threadIdx.x;

    const float2* row = gI + ((size_t)k1 << 13) + b;   // element (k1,i,b) at ((k1<<10)+i)*8 + b
    #pragma unroll
    for (int h = 0; h < 4; h++) {
        int i = tid + (h << 8);
        A[i] = row[(size_t)i << 3];
    }
    #pragma unroll
    for (int h = 0; h < 2; h++) {
        int j = tid + (h << 8);
        float sn, cn;
        __sincosf(6.283185307179586f * (float)j * (1.0f / 1024.0f), &sn, &cn);
        W[j] = make_float2(cn, sn);   // +i for inverse
    }

    fft1024_inv(A, Bb, W, tid);

    // out column xo2 corresponds to x2 = (xo2 + 768) & 1023 (fftshift + crop fold)
    float2* Tb = T + (((size_t)b * 512) << 10) + k1;
    #pragma unroll
    for (int h = 0; h < 2; h++) {
        int xo2 = tid + (h << 8);
        int x2  = (xo2 + 768) & 1023;
        Tb[(size_t)xo2 << 10] = A[x2];
    }
}

// ---------- de-apodization (matches _deapod) ----------
__device__ __forceinline__ float apodf(int n) {
    float x  = ((float)n - 256.0f) * (1.0f / 1024.0f);
    float px = 3.14159265358979f * 6.0f * x;
    float t  = BETAF * BETAF - px * px;
    float st = sqrtf(fabsf(t));
    float num = (t > 0.0f) ? sinhf(st) : __sinf(st);
    return num / fmaxf(st, 1e-6f);
}

// ---------- Pass 2: columns (k1 -> x1), fuse shift/crop/real/de-apod ----------
__global__ __launch_bounds__(256) void fft_pass2(const float2* __restrict__ T,
                                                 float* __restrict__ out)
{
    __shared__ float2 A[1024];
    __shared__ float2 Bb[1024];
    __shared__ float2 W[512];

    int blk = blockIdx.x;
    int b   = blk >> 9;
    int xo2 = blk & 511;
    int tid = threadIdx.x;

    const float2* row = T + (((size_t)b * 512 + xo2) << 10);
    #pragma unroll
    for (int h = 0; h < 4; h++) { int i = tid + (h << 8); A[i] = row[i]; }
    #pragma unroll
    for (int h = 0; h < 2; h++) {
        int j = tid + (h << 8);
        float sn, cn;
        __sincosf(6.283185307179586f * (float)j * (1.0f / 1024.0f), &sn, &cn);
        W[j] = make_float2(cn, sn);
    }

    fft1024_inv(A, Bb, W, tid);

    float a2 = apodf(xo2);
    #pragma unroll
    for (int h = 0; h < 2; h++) {
        int xo1 = tid + (h << 8);
        int x1  = (xo1 + 768) & 1023;
        float a1 = apodf(xo1);
        out[((size_t)b * 512 + xo1) * 512 + xo2] = A[x1].x / (a1 * a2);
    }
}

// ---------- host launch ----------
extern "C" void kernel_launch(void* const* d_in, const int* in_sizes, int n_in,
                              void* d_out, int out_size, void* d_ws, size_t ws_size,
                              hipStream_t stream)
{
    const float* yr  = (const float*)d_in[0];
    const float* yi  = (const float*)d_in[1];
    const float* uv  = (const float*)d_in[2];
    const float* wts = (const float*)d_in[3];

    int M = in_sizes[3];

    const size_t gridBytes = (size_t)KGRID * KGRID * NB * sizeof(float2);  // 64 MB interleaved
    float* gI  = (float*)d_ws;
    float2* T  = (float2*)((char*)d_ws + gridBytes);                       // 32 MB

    hipMemsetAsync(gI, 0, gridBytes, stream);
    grid_kernel<<<dim3(2048), dim3(256), 0, stream>>>(uv, wts, yr, yi, gI, M);
    fft_pass1<<<dim3(NB * 1024), dim3(256), 0, stream>>>((const float2*)gI, T);
    fft_pass2<<<dim3(NB * 512), dim3(256), 0, stream>>>(T, (float*)d_out);
}

// Round 4
// 854.406 us; speedup vs baseline: 6.8656x; 1.0441x over previous
//
#include <hip/hip_runtime.h>
#include <math.h>

#define KGRID 1024
#define NIMG  512
#define JW    6
#define BETAF 14.04f   // 2.34 * J
#define NB    8        // batch count (fixed by problem)
#define TILE  32       // tile side in grid cells
#define NBIN  1024     // (1024/TILE)^2
#define CAP   512      // max point-entries per bin (mean ~264, sigma ~16)

// ---------- Kaiser-Bessel I0 (Abramowitz & Stegun 9.8.1 / 9.8.2, ~2e-7 rel) ----------
__device__ __forceinline__ float i0f_dev(float x) {
    float ax = fabsf(x);
    if (ax < 3.75f) {
        float z = ax * (1.0f / 3.75f);
        z = z * z;
        return 1.0f + z * (3.5156229f + z * (3.0899424f + z * (1.2067492f +
               z * (0.2659732f + z * (0.0360768f + z * 0.0045813f)))));
    } else {
        float z = 3.75f / ax;
        float p = 0.39894228f + z * (0.01328592f + z * (0.00225319f + z * (-0.00157565f +
                  z * (0.00916281f + z * (-0.02057706f + z * (0.02635537f +
                  z * (-0.01647633f + z * 0.00392377f)))))));
        return expf(ax) * rsqrtf(ax) * p;
    }
}

// ---------- Phase A: bin measurements into 32x32-cell tiles (<=4 bins each) ----------
__global__ __launch_bounds__(256) void bin_kernel(const float* __restrict__ uv, int M,
                                                  int* __restrict__ cnt, int* __restrict__ list)
{
    int m = blockIdx.x * 256 + threadIdx.x;
    if (m >= M) return;
    const float c2g = (float)KGRID / 6.283185307179586f;
    float kx = uv[2 * m]     * c2g;
    float ky = uv[2 * m + 1] * c2g;
    int x0 = (int)floorf(kx - 3.0f) + 1;           // leftmost tap, unwrapped
    int y0 = (int)floorf(ky - 3.0f) + 1;
    int x0m = (x0 + 1024) & 1023;
    int y0m = (y0 + 1024) & 1023;
    int txA = x0m >> 5, txB = ((x0m + 5) & 1023) >> 5;
    int tyA = y0m >> 5, tyB = ((y0m + 5) & 1023) >> 5;

    #define PUSH(tx, ty) { int bin = ((tx) << 5) | (ty);                 \
                           int slot = atomicAdd(&cnt[bin], 1);           \
                           if (slot < CAP) list[bin * CAP + slot] = m; }
    PUSH(txA, tyA);
    if (tyB != tyA)  PUSH(txA, tyB);
    if (txB != txA) { PUSH(txB, tyA); if (tyB != tyA) PUSH(txB, tyB); }
    #undef PUSH
}

// ---------- Phase B: per-tile gridding in LDS, single coalesced flush ----------
// Tile = 32x32 cells x 8 batches x float2 = 64KB LDS. Lane l: j2=l>>3, b=l&7.
// ds_add_f32 replaces the 115M global atomics of the scatter version.
__global__ __launch_bounds__(512) void grid_tile(
    const float* __restrict__ uv, const float* __restrict__ wts,
    const float* __restrict__ yr, const float* __restrict__ yi,
    const int* __restrict__ cnt, const int* __restrict__ list,
    float* __restrict__ gI, int M)
{
    __shared__ float S[16384];   // [lx][ly][b][c] : ((lx*32+ly)*8 + b)*2 + c

    int tile = blockIdx.x;
    int tx0 = (tile >> 5) << 5;
    int ty0 = (tile & 31) << 5;
    int tid = threadIdx.x;

    for (int i = tid; i < 16384; i += 512) S[i] = 0.0f;
    __syncthreads();

    int n = cnt[tile]; if (n > CAP) n = CAP;
    const int* lst = list + tile * CAP;

    int wid  = tid >> 6;     // 0..7
    int lane = tid & 63;
    int j2 = lane >> 3;      // 0..7, active if < 6
    int b  = lane & 7;
    bool yact = (j2 < JW);

    float inv = 1.0f / i0f_dev(BETAF);
    float s2 = inv * inv;
    const float c2g = (float)KGRID / 6.283185307179586f;

    int i = wid;
    // software-pipelined point loads: fetch i's data, start i+8 while computing
    float u0 = 0.f, v0 = 0.f, sc0 = 0.f, yr0 = 0.f, yi0 = 0.f;
    if (i < n) {
        int m = lst[i];
        u0 = uv[2 * m]; v0 = uv[2 * m + 1];
        sc0 = wts[m] * s2;
        yr0 = yr[(size_t)b * M + m];
        yi0 = yi[(size_t)b * M + m];
    }
    while (i < n) {
        int i2 = i + 8;
        float u1 = 0.f, v1 = 0.f, sc1 = 0.f, yr1 = 0.f, yi1 = 0.f;
        if (i2 < n) {
            int m1 = lst[i2];
            u1 = uv[2 * m1]; v1 = uv[2 * m1 + 1];
            sc1 = wts[m1] * s2;
            yr1 = yr[(size_t)b * M + m1];
            yi1 = yi[(size_t)b * M + m1];
        }

        float yrl = yr0 * sc0;
        float yil = yi0 * sc0;

        float ky  = v0 * c2g;
        float kmy = floorf(ky - 3.0f);
        float dy  = ky - kmy - 1.0f - (float)j2;
        float ry  = dy * (1.0f / 3.0f);
        float ay  = fmaxf(1.0f - ry * ry, 0.0f);
        float wyl = i0f_dev(BETAF * sqrtf(ay));
        int y0m   = (((int)kmy + 1) + 1024) & 1023;
        int ly    = ((y0m + j2) & 1023) - ty0;
        bool yok  = yact && ((unsigned)ly < 32u);

        float kx  = u0 * c2g;
        float kmx = floorf(kx - 3.0f);
        int x0m   = (((int)kmx + 1) + 1024) & 1023;
        #pragma unroll
        for (int j1 = 0; j1 < JW; j1++) {
            float dx = kx - kmx - 1.0f - (float)j1;
            float rx = dx * (1.0f / 3.0f);
            float axv = fmaxf(1.0f - rx * rx, 0.0f);
            float wx  = i0f_dev(BETAF * sqrtf(axv));
            int lx    = ((x0m + j1) & 1023) - tx0;
            if (yok && ((unsigned)lx < 32u)) {
                float w = wx * wyl;
                int a = (((lx << 5) + ly) << 4) + (b << 1);
                unsafeAtomicAdd(&S[a],     yrl * w);
                unsafeAtomicAdd(&S[a + 1], yil * w);
            }
        }

        u0 = u1; v0 = v1; sc0 = sc1; yr0 = yr1; yi0 = yi1;
        i = i2;
    }
    __syncthreads();

    // flush: local float idx f = lx*512 + rem; global float idx = (tx0+lx)*16384 + ty0*16 + rem
    float4* g4 = (float4*)gI;
    float4* s4 = (float4*)S;
    for (int q = tid; q < 4096; q += 512) {
        int f   = q << 2;
        int lx  = f >> 9;
        int rem = f & 511;
        g4[(((size_t)(tx0 + lx)) << 12) + ((size_t)ty0 << 2) + (rem >> 2)] = s4[q];
    }
}

// ---------- Stockham radix-2 1024-pt inverse (e^{+i}) FFT in LDS ----------
__device__ __forceinline__ void fft1024_inv(float2* X, float2* Y, const float2* W, int tid)
{
    float2* src = X;
    float2* dst = Y;
    #pragma unroll
    for (int stage = 0; stage < 10; stage++) {
        const int s = 1 << stage;
        __syncthreads();
        #pragma unroll
        for (int h = 0; h < 2; h++) {
            int t  = tid + (h << 8);
            int sp = t & ~(s - 1);
            float2 c0 = src[t];
            float2 c1 = src[t + 512];
            float2 sum = make_float2(c0.x + c1.x, c0.y + c1.y);
            float2 dif = make_float2(c0.x - c1.x, c0.y - c1.y);
            float2 w = W[sp];
            dst[t + sp]     = sum;
            dst[t + sp + s] = make_float2(w.x * dif.x - w.y * dif.y,
                                          w.x * dif.y + w.y * dif.x);
        }
        float2* tmp = src; src = dst; dst = tmp;
    }
    __syncthreads();
}

// ---------- Pass 1: rows (k2 -> x2) from interleaved grid; keep 512 shifted
// columns; store transposed planar-per-batch into T ----------
__global__ __launch_bounds__(256) void fft_pass1(const float2* __restrict__ gI,
                                                 float2* __restrict__ T)
{
    __shared__ float2 A[1024];
    __shared__ float2 Bb[1024];
    __shared__ float2 W[512];

    int blk = blockIdx.x;
    int k1  = ((blk >> 6) << 3) | (blk & 7);
    int b   = (blk >> 3) & 7;
    int tid = threadIdx.x;

    const float2* row = gI + ((size_t)k1 << 13) + b;   // (k1,i,b) at ((k1<<10)+i)*8 + b
    #pragma unroll
    for (int h = 0; h < 4; h++) {
        int i = tid + (h << 8);
        A[i] = row[(size_t)i << 3];
    }
    #pragma unroll
    for (int h = 0; h < 2; h++) {
        int j = tid + (h << 8);
        float sn, cn;
        __sincosf(6.283185307179586f * (float)j * (1.0f / 1024.0f), &sn, &cn);
        W[j] = make_float2(cn, sn);   // +i for inverse
    }

    fft1024_inv(A, Bb, W, tid);

    // out column xo2 corresponds to x2 = (xo2 + 768) & 1023 (fftshift + crop fold)
    float2* Tb = T + (((size_t)b * 512) << 10) + k1;
    #pragma unroll
    for (int h = 0; h < 2; h++) {
        int xo2 = tid + (h << 8);
        int x2  = (xo2 + 768) & 1023;
        Tb[(size_t)xo2 << 10] = A[x2];
    }
}

// ---------- de-apodization (matches _deapod) ----------
__device__ __forceinline__ float apodf(int n) {
    float x  = ((float)n - 256.0f) * (1.0f / 1024.0f);
    float px = 3.14159265358979f * 6.0f * x;
    float t  = BETAF * BETAF - px * px;
    float st = sqrtf(fabsf(t));
    float num = (t > 0.0f) ? sinhf(st) : __sinf(st);
    return num / fmaxf(st, 1e-6f);
}

// ---------- Pass 2: columns (k1 -> x1), fuse shift/crop/real/de-apod ----------
__global__ __launch_bounds__(256) void fft_pass2(const float2* __restrict__ T,
                                                 float* __restrict__ out)
{
    __shared__ float2 A[1024];
    __shared__ float2 Bb[1024];
    __shared__ float2 W[512];

    int blk = blockIdx.x;
    int b   = blk >> 9;
    int xo2 = blk & 511;
    int tid = threadIdx.x;

    const float2* row = T + (((size_t)b * 512 + xo2) << 10);
    #pragma unroll
    for (int h = 0; h < 4; h++) { int i = tid + (h << 8); A[i] = row[i]; }
    #pragma unroll
    for (int h = 0; h < 2; h++) {
        int j = tid + (h << 8);
        float sn, cn;
        __sincosf(6.283185307179586f * (float)j * (1.0f / 1024.0f), &sn, &cn);
        W[j] = make_float2(cn, sn);
    }

    fft1024_inv(A, Bb, W, tid);

    float a2 = apodf(xo2);
    #pragma unroll
    for (int h = 0; h < 2; h++) {
        int xo1 = tid + (h << 8);
        int x1  = (xo1 + 768) & 1023;
        float a1 = apodf(xo1);
        out[((size_t)b * 512 + xo1) * 512 + xo2] = A[x1].x / (a1 * a2);
    }
}

// ---------- host launch ----------
extern "C" void kernel_launch(void* const* d_in, const int* in_sizes, int n_in,
                              void* d_out, int out_size, void* d_ws, size_t ws_size,
                              hipStream_t stream)
{
    const float* yr  = (const float*)d_in[0];
    const float* yi  = (const float*)d_in[1];
    const float* uv  = (const float*)d_in[2];
    const float* wts = (const float*)d_in[3];

    int M = in_sizes[3];

    const size_t gridBytes = (size_t)KGRID * KGRID * NB * sizeof(float2);  // 64 MB interleaved
    float*  gI   = (float*)d_ws;
    char*   p2   = (char*)d_ws + gridBytes;
    float2* T    = (float2*)p2;                 // 32 MB, used by pass1/pass2
    // bin scratch ALIASES T's region (temporally disjoint: bins die before pass1 writes T)
    int*    cnt  = (int*)p2;                    // 4 KB
    int*    list = (int*)(p2 + 4096);           // 2 MB

    hipMemsetAsync(cnt, 0, NBIN * sizeof(int), stream);
    bin_kernel<<<dim3((M + 255) / 256), dim3(256), 0, stream>>>(uv, M, cnt, list);
    grid_tile<<<dim3(NBIN), dim3(512), 0, stream>>>(uv, wts, yr, yi, cnt, list, gI, M);
    fft_pass1<<<dim3(NB * 1024), dim3(256), 0, stream>>>((const float2*)gI, T);
    fft_pass2<<<dim3(NB * 512), dim3(256), 0, stream>>>(T, (float*)d_out);
}